// Round 8
// baseline (2623.022 us; speedup 1.0000x reference)
//
#include <hip/hip_runtime.h>
#include <hip/hip_bf16.h>
#include <cstddef>

typedef __attribute__((ext_vector_type(8))) short short8;
typedef __attribute__((ext_vector_type(4))) float f32x4;
typedef unsigned short u16;
typedef unsigned int u32;

#define Bc 16
#define Tt 32
#define Hh 40
#define Ww 40
#define Fc 40
#define NPIX (Bc*Hh*Ww)   // 25600
#define BN_EPS_ 1e-3f
#define SMEM_U16 26240    // 52.5 KB

__device__ __forceinline__ float hsig(float x) {
    return fminf(fmaxf(0.2f * x + 0.5f, 0.0f), 1.0f);
}
__device__ __forceinline__ u16 f2b(float f) {
    __hip_bfloat16 h = __float2bfloat16(f);
    return __builtin_bit_cast(u16, h);
}
__device__ __forceinline__ float b2f(u16 u) {
    return __builtin_bit_cast(float, (u32)u << 16);
}

// ---------------------------------------------------------------------------
// Pack [Wx ; Wh] -> bf16 weights in per-wave MFMA B-fragment order:
//   idx = ((((ng*NKO2 + step)*5 + nt)*64 + lane)*8 + j)
//   n = ng*80 + nt*16 + (lane&15);  k = step*32 + (lane>>4)*8 + j
// Zero for k >= K and for padded Wx channels -> tail A x zero B contributes 0.
// ---------------------------------------------------------------------------
template <int XPAD, int CIN, int NKO2>
__global__ __launch_bounds__(256) void build_wf(const float* __restrict__ Wx,
                                                const float* __restrict__ Wh,
                                                u16* __restrict__ Wf)
{
    constexpr int KPOS = XPAD + Fc;
    constexpr int K    = 9 * KPOS;
    int idx = blockIdx.x * 256 + threadIdx.x;
    if (idx >= 2 * NKO2 * 5 * 64 * 8) return;
    int j    = idx & 7;
    int lane = (idx >> 3) & 63;
    int rest = idx >> 9;
    int nt   = rest % 5;  rest /= 5;
    int step = rest % NKO2; rest /= NKO2;
    int ng   = rest;
    int n = ng * 80 + nt * 16 + (lane & 15);
    int k = step * 32 + (lane >> 4) * 8 + j;
    float v = 0.0f;
    if (k < K) {
        int pos = k / KPOS, cc = k - pos * KPOS;
        if (cc < XPAD) {
            v = (cc < CIN) ? Wx[(pos * CIN + cc) * 160 + n] : 0.0f;
        } else {
            v = Wh[(pos * Fc + (cc - XPAD)) * 160 + n];
        }
    }
    Wf[idx] = f2b(v);
}

// ---------------------------------------------------------------------------
// Branchless, software-pipelined K-loop. B fragments streamed from L2
// (coalesced dwordx4, fragment-ordered), A fragments from LDS halo.
// Double-buffered prefetch: step s+1 loads issue before step s MFMAs.
// Tail safety: k clamped to 9*KPOS-8 (8-ALIGNED) before pos/cc decompose,
// so the full short8 read lands on initialized halo data (finite); B==0
// beyond K zeroes the contribution exactly.
// (Round-6 bug: pos-clamp left cc>=KPOS -> OOB. Round-7 bug: k-clamp to
//  KPOS*9-1 was not 8-aligned -> short8 read ran 7 u16 past the halo into
//  uninitialized LDS -> bf16-NaN bit patterns -> NaN*0 = NaN in MFMA.)
// ---------------------------------------------------------------------------
template <int KPOS, int XPAD, int NKO2>
__device__ __forceinline__ void kloop(const u16* __restrict__ Xs,
                                      const u16* __restrict__ Hs,
                                      const u16* __restrict__ wf,
                                      const int* py, const int* px,
                                      int lquad, f32x4 acc[5][5])
{
    constexpr int KMAXA = 9 * KPOS - 8;     // aligned clamp target
    static_assert(KMAXA % 8 == 0, "clamp must preserve fragment alignment");
    short8 a[2][5], b[2][5];

    auto loadB = [&](int step, short8* dst) {
#pragma unroll
        for (int nt = 0; nt < 5; ++nt)
            dst[nt] = *reinterpret_cast<const short8*>(wf + (size_t)(step * 5 + nt) * 512);
    };
    auto loadA = [&](int step, short8* dst) {
        int k = step * 32 + lquad * 8;
        k = (k > KMAXA) ? KMAXA : k;        // finite A (real halo data), zero B
        int pos = k / KPOS;
        int cc  = k - pos * KPOS;
        int dy = pos / 3, dx = pos - dy * 3;
        const u16* base; int ch, str;
        if (cc < XPAD) { base = Xs; ch = cc;        str = XPAD; }
        else           { base = Hs; ch = cc - XPAD; str = Fc;   }
#pragma unroll
        for (int mt = 0; mt < 5; ++mt)
            dst[mt] = *reinterpret_cast<const short8*>(
                &base[((py[mt] + dy) * 42 + px[mt] + dx) * str + ch]);
    };

    loadA(0, a[0]);
    loadB(0, b[0]);

#pragma unroll
    for (int s = 0; s < NKO2; ++s) {
        const int nb = (s + 1 < NKO2) ? s + 1 : s;
        loadB(nb, b[(s + 1) & 1]);
        loadA(nb, a[(s + 1) & 1]);
#pragma unroll
        for (int mt = 0; mt < 5; ++mt)
#pragma unroll
            for (int nt = 0; nt < 5; ++nt)
                acc[mt][nt] = __builtin_amdgcn_mfma_f32_16x16x32_bf16(
                    a[s & 1][mt], b[s & 1][nt], acc[mt][nt], 0, 0, 0);
    }
}

// ---------------------------------------------------------------------------
// Diagonal-pipelined ConvLSTM step: up to 4 (layer,t) stages per launch.
// Per stage: 160 blocks, M-tile 160 pixels (4 rows), N=160 gates.
// ---------------------------------------------------------------------------
struct Stage {
    const void* xin;   // l==0: fp32 input base; l>=1: bf16 X-ring slot
    const u16* hin;    // bf16 [NPIX][40]
    u16*       hout;
    float*     cst;    // fp32 [NPIX][40]
    const u16* wf;     // fragment-ordered weights
    const float* bias; const float* ga; const float* be;
    const float* mu;   const float* va;
    u16*       xout;
    int layer; int t;
};
struct DiagArgs { Stage s[4]; };

__global__ __launch_bounds__(256, 2) void diag_step(DiagArgs args)
{
    // max(halo 40320 B, zs 80*164*4 = 52480 B) -> 52.5 KB
    __shared__ __align__(16) u16 smem[SMEM_U16];

    const int sidx = blockIdx.x / 160;
    const int blk  = blockIdx.x - sidx * 160;
    const Stage& st = args.s[sidx];
    const int l    = st.layer;
    const int XPAD = (l == 0) ? 8 : 40;

    u16* Xs = smem;
    u16* Hs = smem + 6 * 42 * XPAD;
    float* zs = reinterpret_cast<float*>(smem);   // epilogue overlay

    const int tid   = threadIdx.x;
    const int P0    = blk * 160;
    const int bimg  = P0 / 1600;
    const int P0l   = P0 - bimg * 1600;
    const int P0row = P0l / 40;            // 0,4,...,36

    // ---- stage Hs halo: 6 rows x 42 cols x 40 ch ----
    const u16* hp = st.hin + (size_t)bimg * 1600 * Fc;
    for (int i = tid; i < 6 * 40 * 10; i += 256) {
        int s = i / 400, rem = i - s * 400;
        int px_ = rem / 10, c4 = rem - px_ * 10;
        int gy = P0row - 1 + s;
        uint2 v = make_uint2(0u, 0u);
        if (gy >= 0 && gy < Hh)
            v = *reinterpret_cast<const uint2*>(hp + ((size_t)gy * Ww + px_) * Fc + c4 * 4);
        *reinterpret_cast<uint2*>(&Hs[(s * 42 + px_ + 1) * Fc + c4 * 4]) = v;
    }
    for (int i = tid; i < 6 * 2 * 10; i += 256) {
        int s = i / 20, rem = i - s * 20;
        int side = rem / 10, c4 = rem - side * 10;
        *reinterpret_cast<uint2*>(&Hs[(s * 42 + (side ? 41 : 0)) * Fc + c4 * 4]) =
            make_uint2(0u, 0u);
    }

    // ---- stage Xs halo ----
    if (l == 0) {
        const float* xf = (const float*)st.xin + (size_t)(bimg * Tt + st.t) * 1600;
        for (int i = tid; i < 6 * 42; i += 256) {
            int s = i / 42, xc = i - s * 42;
            int gy = P0row - 1 + s, gx = xc - 1;
            u16 tmp[8] = {0, 0, 0, 0, 0, 0, 0, 0};
            if (gy >= 0 && gy < Hh && gx >= 0 && gx < Ww)
                tmp[0] = f2b(xf[(size_t)gy * Ww + gx]);
            *reinterpret_cast<uint4*>(&Xs[(s * 42 + xc) * 8]) =
                *reinterpret_cast<const uint4*>(tmp);
        }
    } else {
        const u16* xb = (const u16*)st.xin + (size_t)bimg * 1600 * Fc;
        for (int i = tid; i < 6 * 40 * 10; i += 256) {
            int s = i / 400, rem = i - s * 400;
            int px_ = rem / 10, c4 = rem - px_ * 10;
            int gy = P0row - 1 + s;
            uint2 v = make_uint2(0u, 0u);
            if (gy >= 0 && gy < Hh)
                v = *reinterpret_cast<const uint2*>(xb + ((size_t)gy * Ww + px_) * Fc + c4 * 4);
            *reinterpret_cast<uint2*>(&Xs[(s * 42 + px_ + 1) * Fc + c4 * 4]) = v;
        }
        for (int i = tid; i < 6 * 2 * 10; i += 256) {
            int s = i / 20, rem = i - s * 20;
            int side = rem / 10, c4 = rem - side * 10;
            *reinterpret_cast<uint2*>(&Xs[(s * 42 + (side ? 41 : 0)) * Fc + c4 * 4]) =
                make_uint2(0u, 0u);
        }
    }

    // ---- zero the smem gap past the halo: any stray in-smem read is finite ----
    {
        const int hs_end = 6 * 42 * (XPAD + Fc);      // u16 offset of halo end
        for (int i = hs_end / 8 + tid; i < SMEM_U16 / 8; i += 256)
            *reinterpret_cast<uint4*>(&smem[i * 8]) = make_uint4(0u, 0u, 0u, 0u);
    }

    // ---- wave constants ----
    const int lane  = tid & 63;
    const int wid   = tid >> 6;
    const int mg    = wid & 1;
    const int ng    = wid >> 1;
    const int lcol  = lane & 15;
    const int lquad = lane >> 4;

    int py[5], px[5];
#pragma unroll
    for (int mt = 0; mt < 5; ++mt) {
        int mrow = mg * 80 + mt * 16 + lcol;
        py[mt] = mrow / 40;
        px[mt] = mrow - py[mt] * 40;
    }

    f32x4 acc[5][5] = {};

    __syncthreads();   // halos staged; K-loop is barrier-free

    if (l == 0) {
        const u16* wf = st.wf + (size_t)ng * 14 * 5 * 512 + (size_t)lane * 8;
        kloop<48, 8, 14>(Xs, Hs, wf, py, px, lquad, acc);
    } else {
        const u16* wf = st.wf + (size_t)ng * 24 * 5 * 512 + (size_t)lane * 8;
        kloop<80, 40, 24>(Xs, Hs, wf, py, px, lquad, acc);
    }

    __syncthreads();   // all waves done reading halo LDS before zs overlay

    // ---- epilogue in two 80-row chunks (zs overlays smem) ----
    u16* hob = st.hout;
    float* cb = st.cst;
    u16* xob = (l == 3)
        ? st.xout + ((size_t)(bimg * Tt + st.t) * 1600 + P0l) * Fc
        : st.xout + ((size_t)bimg * 1600 + P0l) * Fc;

    for (int q = 0; q < 2; ++q) {
        if (mg == q) {
#pragma unroll
            for (int mt = 0; mt < 5; ++mt)
#pragma unroll
                for (int nt = 0; nt < 5; ++nt) {
                    int mr   = mt * 16 + lquad * 4;
                    int ncol = ng * 80 + nt * 16 + lcol;
#pragma unroll
                    for (int r = 0; r < 4; ++r)
                        zs[(mr + r) * 164 + ncol] = acc[mt][nt][r];
                }
        }
        __syncthreads();
        for (int i = tid; i < 3200; i += 256) {
            int m = i / 40, f = i - m * 40;
            float zi = zs[m * 164 + f]        + st.bias[f];
            float zf = zs[m * 164 + 40 + f]   + st.bias[40 + f];
            float zg = zs[m * 164 + 80 + f]   + st.bias[80 + f];
            float zo = zs[m * 164 + 120 + f]  + st.bias[120 + f];
            int pl = q * 80 + m;
            size_t gp = (size_t)(P0 + pl) * Fc + f;
            float cold = cb[gp];
            float cn = hsig(zf) * cold + hsig(zi) * tanhf(zg);
            float hn = hsig(zo) * tanhf(cn);
            cb[gp] = cn;
            hob[gp] = f2b(hn);
            float sc = st.ga[f] * rsqrtf(st.va[f] + BN_EPS_);
            xob[(size_t)pl * Fc + f] = f2b((hn - st.mu[f]) * sc + st.be[f]);
        }
        __syncthreads();   // zs reads done before next chunk's overwrite
    }
}

// ---------------------------------------------------------------------------
// Conv3D (3x3x3 SAME) + bias + sigmoid, bf16 in, fp32 out. XCD-aware swizzle.
// 4 independent accumulators to break the fmaf dependency chain.
// ---------------------------------------------------------------------------
__global__ __launch_bounds__(320) void conv3d_sig_bf16(
    const u16* __restrict__ X,        // bf16 [B,T,1600,40]
    const float* __restrict__ W3,     // [3,3,3,40,1]
    const float* __restrict__ b3,
    float* __restrict__ out)          // [B,T,1600]
{
    __shared__ float ws[27 * Fc];
    for (int i = threadIdx.x; i < 27 * Fc; i += 320) ws[i] = W3[i];
    __syncthreads();

    const int bid   = blockIdx.x;           // 2560 blocks
    const int xcd   = bid & 7;
    const int local = bid >> 3;             // 0..319
    const int b     = xcd * 2 + (local / 160);
    const int rem   = local - (local / 160) * 160;
    const int t     = rem / 5;
    const int s     = rem - t * 5;
    const int pix   = s * 320 + threadIdx.x;
    const int y     = pix / 40;
    const int x     = pix - y * 40;

    float a0 = b3[0], a1 = 0.f, a2 = 0.f, a3 = 0.f;
    for (int dt = 0; dt < 3; ++dt) {
        int tc = t + dt - 1;
        if (tc < 0 || tc >= Tt) continue;
        for (int dy = 0; dy < 3; ++dy) {
            int yy = y + dy - 1;
            if (yy < 0 || yy >= Hh) continue;
            for (int dx = 0; dx < 3; ++dx) {
                int xx = x + dx - 1;
                if (xx < 0 || xx >= Ww) continue;
                const u16* xp = X + ((size_t)(b * Tt + tc) * 1600 + yy * 40 + xx) * Fc;
                const float* wp = ws + ((dt * 3 + dy) * 3 + dx) * Fc;
#pragma unroll
                for (int c4 = 0; c4 < Fc; c4 += 4) {
                    ushort4 v = *reinterpret_cast<const ushort4*>(xp + c4);
                    a0 = fmaf(b2f(v.x), wp[c4 + 0], a0);
                    a1 = fmaf(b2f(v.y), wp[c4 + 1], a1);
                    a2 = fmaf(b2f(v.z), wp[c4 + 2], a2);
                    a3 = fmaf(b2f(v.w), wp[c4 + 3], a3);
                }
            }
        }
    }
    float acc = (a0 + a1) + (a2 + a3);
    out[((size_t)(b * Tt + t) * 1600 + pix)] = 1.0f / (1.0f + expf(-acc));
}

// ---------------------------------------------------------------------------
extern "C" void kernel_launch(void* const* d_in, const int* in_sizes, int n_in,
                              void* d_out, int out_size, void* d_ws, size_t ws_size,
                              hipStream_t stream)
{
    const float* inp = (const float*)d_in[0];

    char* p = (char*)d_ws;
    const size_t x3sz   = (size_t)Bc * Tt * 1600 * Fc * sizeof(u16);  // 65,536,000
    const size_t slotsz = (size_t)Bc * 1600 * Fc * sizeof(u16);       //  2,048,000
    const size_t csz    = (size_t)NPIX * Fc * sizeof(float);          //  4,096,000
    const size_t wfsz   = (size_t)2 * 24 * 5 * 64 * 8 * sizeof(u16);  //    245,760

    u16* X3 = (u16*)p;                       p += x3sz;
    u16* xr[3];
    for (int l = 0; l < 3; ++l) { xr[l] = (u16*)p; p += 2 * slotsz; }
    u16* hb[8];
    for (int i = 0; i < 8; ++i) { hb[i] = (u16*)p; p += slotsz; }
    float* cbuf[4];
    for (int l = 0; l < 4; ++l) { cbuf[l] = (float*)p; p += csz; }
    u16* wf[4];
    for (int l = 0; l < 4; ++l) { wf[l] = (u16*)p; p += wfsz; }
    // total ~112 MB

    for (int l = 0; l < 4; ++l) {
        const float* Wx = (const float*)d_in[1 + 7 * l + 0];
        const float* Wh = (const float*)d_in[1 + 7 * l + 1];
        if (l == 0)
            build_wf<8, 1, 14><<<(2 * 14 * 5 * 512 + 255) / 256, 256, 0, stream>>>(Wx, Wh, wf[l]);
        else
            build_wf<40, 40, 24><<<(2 * 24 * 5 * 512 + 255) / 256, 256, 0, stream>>>(Wx, Wh, wf[l]);
        hipMemsetAsync(hb[l * 2], 0, slotsz, stream);
        hipMemsetAsync(cbuf[l], 0, csz, stream);
    }

    // ---- 35 diagonals: d = l + t ----
    for (int d = 0; d < Tt + 3; ++d) {
        DiagArgs da;
        int na = 0;
        for (int l = 0; l < 4; ++l) {
            int t = d - l;
            if (t < 0 || t >= Tt) continue;
            Stage& s = da.s[na++];
            s.layer = l; s.t = t;
            s.hin  = hb[l * 2 + (t & 1)];
            s.hout = hb[l * 2 + ((t + 1) & 1)];
            s.cst  = cbuf[l];
            s.wf   = wf[l];
            s.bias = (const float*)d_in[1 + 7 * l + 2];
            s.ga   = (const float*)d_in[1 + 7 * l + 3];
            s.be   = (const float*)d_in[1 + 7 * l + 4];
            s.mu   = (const float*)d_in[1 + 7 * l + 5];
            s.va   = (const float*)d_in[1 + 7 * l + 6];
            s.xin  = (l == 0) ? (const void*)inp
                              : (const void*)(xr[l - 1] + (size_t)(t & 1) * (slotsz / 2));
            s.xout = (l == 3) ? X3 : xr[l] + (size_t)(t & 1) * (slotsz / 2);
        }
        diag_step<<<na * 160, 256, 0, stream>>>(da);
    }

    conv3d_sig_bf16<<<2560, 320, 0, stream>>>(
        X3, (const float*)d_in[29], (const float*)d_in[30], (float*)d_out);
}

// Round 9
// 2372.833 us; speedup vs baseline: 1.1054x; 1.1054x over previous
//
#include <hip/hip_runtime.h>
#include <hip/hip_bf16.h>
#include <cstddef>

typedef __attribute__((ext_vector_type(8))) short short8;
typedef __attribute__((ext_vector_type(4))) float f32x4;
typedef unsigned short u16;
typedef unsigned int u32;

#define Bc 16
#define Tt 32
#define Hh 40
#define Ww 40
#define Fc 40
#define NPIX (Bc*Hh*Ww)   // 25600
#define BN_EPS_ 1e-3f

__device__ __forceinline__ float hsig(float x) {
    return fminf(fmaxf(0.2f * x + 0.5f, 0.0f), 1.0f);
}
__device__ __forceinline__ u16 f2b(float f) {
    __hip_bfloat16 h = __float2bfloat16(f);
    return __builtin_bit_cast(u16, h);
}
__device__ __forceinline__ float b2f(u16 u) {
    return __builtin_bit_cast(float, (u32)u << 16);
}

// ---------------------------------------------------------------------------
// Fragment-order weight packing (device fn). Same mapping as rounds 5-8:
//   idx = ((((ng*NKO2 + step)*5 + nt)*64 + lane)*8 + j)
//   n = ng*80 + nt*16 + (lane&15);  k = step*32 + (lane>>4)*8 + j
// Zero for k >= K and padded Wx channels.
// ---------------------------------------------------------------------------
template <int XPAD, int CIN, int NKO2>
__device__ __forceinline__ void pack_one(const float* __restrict__ Wx,
                                         const float* __restrict__ Wh,
                                         u16* __restrict__ Wf, int idx)
{
    constexpr int KPOS = XPAD + Fc;
    constexpr int K    = 9 * KPOS;
    int j    = idx & 7;
    int lane = (idx >> 3) & 63;
    int rest = idx >> 9;
    int nt   = rest % 5;  rest /= 5;
    int step = rest % NKO2; rest /= NKO2;
    int ng   = rest;
    int n = ng * 80 + nt * 16 + (lane & 15);
    int k = step * 32 + (lane >> 4) * 8 + j;
    float v = 0.0f;
    if (k < K) {
        int pos = k / KPOS, cc = k - pos * KPOS;
        if (cc < XPAD) {
            v = (cc < CIN) ? Wx[(pos * CIN + cc) * 160 + n] : 0.0f;
        } else {
            v = Wh[(pos * Fc + (cc - XPAD)) * 160 + n];
        }
    }
    Wf[idx] = f2b(v);
}

// ---------------------------------------------------------------------------
// Single init kernel: packs all 4 layers' weights + zeroes h_even/cbuf region.
// Replaces 4 build_wf launches + 12 hipMemsetAsync (graph-node trim).
// ---------------------------------------------------------------------------
struct InitArgs {
    const float* Wx[4]; const float* Wh[4];
    u16* wf[4];
    float4* zb;        // contiguous zero region (h_even x4 + cbuf x4)
    int zb_quads;      // float4 count
};

__global__ __launch_bounds__(256) void init_all(InitArgs a)
{
    const int gid    = blockIdx.x * 256 + threadIdx.x;
    const int stride = gridDim.x * 256;
    for (int i = gid; i < 2 * 14 * 5 * 512; i += stride)
        pack_one<8, 1, 14>(a.Wx[0], a.Wh[0], a.wf[0], i);
    for (int l = 1; l < 4; ++l)
        for (int i = gid; i < 2 * 24 * 5 * 512; i += stride)
            pack_one<40, 40, 24>(a.Wx[l], a.Wh[l], a.wf[l], i);
    const float4 z = make_float4(0.f, 0.f, 0.f, 0.f);
    for (int i = gid; i < a.zb_quads; i += stride) a.zb[i] = z;
}

// ---------------------------------------------------------------------------
// Round-5 K-loop (measured best): barrier-free, B streamed from L2 via
// coalesced dwordx4 in fragment order, A from LDS halo, pos<9 guard with
// zero-init fragments for the tail. NSTEPS trims the all-zero final step.
// ---------------------------------------------------------------------------
template <int KPOS, int XPAD, int NSTEPS>
__device__ __forceinline__ void kloop(const u16* __restrict__ Xs,
                                      const u16* __restrict__ Hs,
                                      const u16* __restrict__ wf,
                                      const int* py, const int* px,
                                      int lquad, f32x4 acc[5][5])
{
#pragma unroll 2
    for (int step = 0; step < NSTEPS; ++step) {
        short8 bfr[5];
#pragma unroll
        for (int nt = 0; nt < 5; ++nt)
            bfr[nt] = *reinterpret_cast<const short8*>(wf + (size_t)(step * 5 + nt) * 512);

        const int k   = step * 32 + lquad * 8;
        const int pos = k / KPOS;
        const int cc  = k - pos * KPOS;
        short8 afr[5] = {};
        if (pos < 9) {
            const int dy = pos / 3, dx = pos - dy * 3;
            const u16* base; int ch, str;
            if (cc < XPAD) { base = Xs; ch = cc;        str = XPAD; }
            else           { base = Hs; ch = cc - XPAD; str = Fc;   }
#pragma unroll
            for (int mt = 0; mt < 5; ++mt)
                afr[mt] = *reinterpret_cast<const short8*>(
                    &base[((py[mt] + dy) * 42 + px[mt] + dx) * str + ch]);
        }
#pragma unroll
        for (int mt = 0; mt < 5; ++mt)
#pragma unroll
            for (int nt = 0; nt < 5; ++nt)
                acc[mt][nt] = __builtin_amdgcn_mfma_f32_16x16x32_bf16(
                    afr[mt], bfr[nt], acc[mt][nt], 0, 0, 0);
    }
}

// ---------------------------------------------------------------------------
// Diagonal-pipelined ConvLSTM step: up to 4 (layer,t) stages per launch.
// Per stage: 160 blocks, M-tile 160 pixels (4 rows), N=160 gates.
// ---------------------------------------------------------------------------
struct Stage {
    const void* xin;   // l==0: fp32 input base; l>=1: bf16 X-ring slot
    const u16* hin;    // bf16 [NPIX][40]
    u16*       hout;
    float*     cst;    // fp32 [NPIX][40]
    const u16* wf;     // fragment-ordered weights
    const float* bias; const float* ga; const float* be;
    const float* mu;   const float* va;
    u16*       xout;
    int layer; int t;
};
struct DiagArgs { Stage s[4]; };

__global__ __launch_bounds__(256, 2) void diag_step(DiagArgs args)
{
    // max(halo 40320 B, zs 80*164*4 = 52480 B) -> 52.5 KB
    __shared__ __align__(16) u16 smem[26240];

    const int sidx = blockIdx.x / 160;
    const int blk  = blockIdx.x - sidx * 160;
    const Stage& st = args.s[sidx];
    const int l    = st.layer;
    const int XPAD = (l == 0) ? 8 : 40;

    u16* Xs = smem;
    u16* Hs = smem + 6 * 42 * XPAD;
    float* zs = reinterpret_cast<float*>(smem);   // epilogue overlay

    const int tid   = threadIdx.x;
    const int P0    = blk * 160;
    const int bimg  = P0 / 1600;
    const int P0l   = P0 - bimg * 1600;
    const int P0row = P0l / 40;            // 0,4,...,36

    // ---- stage Hs halo: 6 rows x 42 cols x 40 ch ----
    const u16* hp = st.hin + (size_t)bimg * 1600 * Fc;
    for (int i = tid; i < 6 * 40 * 10; i += 256) {
        int s = i / 400, rem = i - s * 400;
        int px_ = rem / 10, c4 = rem - px_ * 10;
        int gy = P0row - 1 + s;
        uint2 v = make_uint2(0u, 0u);
        if (gy >= 0 && gy < Hh)
            v = *reinterpret_cast<const uint2*>(hp + ((size_t)gy * Ww + px_) * Fc + c4 * 4);
        *reinterpret_cast<uint2*>(&Hs[(s * 42 + px_ + 1) * Fc + c4 * 4]) = v;
    }
    for (int i = tid; i < 6 * 2 * 10; i += 256) {
        int s = i / 20, rem = i - s * 20;
        int side = rem / 10, c4 = rem - side * 10;
        *reinterpret_cast<uint2*>(&Hs[(s * 42 + (side ? 41 : 0)) * Fc + c4 * 4]) =
            make_uint2(0u, 0u);
    }

    // ---- stage Xs halo ----
    if (l == 0) {
        const float* xf = (const float*)st.xin + (size_t)(bimg * Tt + st.t) * 1600;
        for (int i = tid; i < 6 * 42; i += 256) {
            int s = i / 42, xc = i - s * 42;
            int gy = P0row - 1 + s, gx = xc - 1;
            u16 tmp[8] = {0, 0, 0, 0, 0, 0, 0, 0};
            if (gy >= 0 && gy < Hh && gx >= 0 && gx < Ww)
                tmp[0] = f2b(xf[(size_t)gy * Ww + gx]);
            *reinterpret_cast<uint4*>(&Xs[(s * 42 + xc) * 8]) =
                *reinterpret_cast<const uint4*>(tmp);
        }
    } else {
        const u16* xb = (const u16*)st.xin + (size_t)bimg * 1600 * Fc;
        for (int i = tid; i < 6 * 40 * 10; i += 256) {
            int s = i / 400, rem = i - s * 400;
            int px_ = rem / 10, c4 = rem - px_ * 10;
            int gy = P0row - 1 + s;
            uint2 v = make_uint2(0u, 0u);
            if (gy >= 0 && gy < Hh)
                v = *reinterpret_cast<const uint2*>(xb + ((size_t)gy * Ww + px_) * Fc + c4 * 4);
            *reinterpret_cast<uint2*>(&Xs[(s * 42 + px_ + 1) * Fc + c4 * 4]) = v;
        }
        for (int i = tid; i < 6 * 2 * 10; i += 256) {
            int s = i / 20, rem = i - s * 20;
            int side = rem / 10, c4 = rem - side * 10;
            *reinterpret_cast<uint2*>(&Xs[(s * 42 + (side ? 41 : 0)) * Fc + c4 * 4]) =
                make_uint2(0u, 0u);
        }
    }

    // ---- wave constants ----
    const int lane  = tid & 63;
    const int wid   = tid >> 6;
    const int mg    = wid & 1;
    const int ng    = wid >> 1;
    const int lcol  = lane & 15;
    const int lquad = lane >> 4;

    int py[5], px[5];
#pragma unroll
    for (int mt = 0; mt < 5; ++mt) {
        int mrow = mg * 80 + mt * 16 + lcol;
        py[mt] = mrow / 40;
        px[mt] = mrow - py[mt] * 40;
    }

    f32x4 acc[5][5] = {};

    __syncthreads();   // halos staged; K-loop is barrier-free

    if (l == 0) {
        const u16* wf = st.wf + (size_t)ng * 14 * 5 * 512 + (size_t)lane * 8;
        kloop<48, 8, 14>(Xs, Hs, wf, py, px, lquad, acc);
    } else {
        // allocated stride is 24 steps; step 23 is all-zero B -> run 23 only
        const u16* wf = st.wf + (size_t)ng * 24 * 5 * 512 + (size_t)lane * 8;
        kloop<80, 40, 23>(Xs, Hs, wf, py, px, lquad, acc);
    }

    __syncthreads();   // all waves done reading halo LDS before zs overlay

    // ---- epilogue in two 80-row chunks (zs overlays smem) ----
    u16* hob = st.hout;
    float* cb = st.cst;
    u16* xob = (l == 3)
        ? st.xout + ((size_t)(bimg * Tt + st.t) * 1600 + P0l) * Fc
        : st.xout + ((size_t)bimg * 1600 + P0l) * Fc;

    for (int q = 0; q < 2; ++q) {
        if (mg == q) {
#pragma unroll
            for (int mt = 0; mt < 5; ++mt)
#pragma unroll
                for (int nt = 0; nt < 5; ++nt) {
                    int mr   = mt * 16 + lquad * 4;
                    int ncol = ng * 80 + nt * 16 + lcol;
#pragma unroll
                    for (int r = 0; r < 4; ++r)
                        zs[(mr + r) * 164 + ncol] = acc[mt][nt][r];
                }
        }
        __syncthreads();
        for (int i = tid; i < 3200; i += 256) {
            int m = i / 40, f = i - m * 40;
            float zi = zs[m * 164 + f]        + st.bias[f];
            float zf = zs[m * 164 + 40 + f]   + st.bias[40 + f];
            float zg = zs[m * 164 + 80 + f]   + st.bias[80 + f];
            float zo = zs[m * 164 + 120 + f]  + st.bias[120 + f];
            int pl = q * 80 + m;
            size_t gp = (size_t)(P0 + pl) * Fc + f;
            float cold = cb[gp];
            float cn = hsig(zf) * cold + hsig(zi) * tanhf(zg);
            float hn = hsig(zo) * tanhf(cn);
            cb[gp] = cn;
            hob[gp] = f2b(hn);
            float sc = st.ga[f] * rsqrtf(st.va[f] + BN_EPS_);
            xob[(size_t)pl * Fc + f] = f2b((hn - st.mu[f]) * sc + st.be[f]);
        }
        __syncthreads();   // zs reads done before next chunk's overwrite
    }
}

// ---------------------------------------------------------------------------
// Conv3D (3x3x3 SAME) + bias + sigmoid, bf16 in, fp32 out. XCD-aware swizzle.
// ROUND-5 VERSION restored: single accumulator (VGPR 36, 79 us measured);
// the 4-acc split (r8) dropped VGPR to 24 and exposed load latency (270 us).
// ---------------------------------------------------------------------------
__global__ __launch_bounds__(320) void conv3d_sig_bf16(
    const u16* __restrict__ X,        // bf16 [B,T,1600,40]
    const float* __restrict__ W3,     // [3,3,3,40,1]
    const float* __restrict__ b3,
    float* __restrict__ out)          // [B,T,1600]
{
    __shared__ float ws[27 * Fc];
    for (int i = threadIdx.x; i < 27 * Fc; i += 320) ws[i] = W3[i];
    __syncthreads();

    const int bid   = blockIdx.x;           // 2560 blocks
    const int xcd   = bid & 7;
    const int local = bid >> 3;             // 0..319
    const int b     = xcd * 2 + (local / 160);
    const int rem   = local - (local / 160) * 160;
    const int t     = rem / 5;
    const int s     = rem - t * 5;
    const int pix   = s * 320 + threadIdx.x;
    const int y     = pix / 40;
    const int x     = pix - y * 40;

    float acc = b3[0];
    for (int dt = 0; dt < 3; ++dt) {
        int tc = t + dt - 1;
        if (tc < 0 || tc >= Tt) continue;
        for (int dy = 0; dy < 3; ++dy) {
            int yy = y + dy - 1;
            if (yy < 0 || yy >= Hh) continue;
            for (int dx = 0; dx < 3; ++dx) {
                int xx = x + dx - 1;
                if (xx < 0 || xx >= Ww) continue;
                const u16* xp = X + ((size_t)(b * Tt + tc) * 1600 + yy * 40 + xx) * Fc;
                const float* wp = ws + ((dt * 3 + dy) * 3 + dx) * Fc;
#pragma unroll
                for (int c4 = 0; c4 < Fc; c4 += 4) {
                    ushort4 v = *reinterpret_cast<const ushort4*>(xp + c4);
                    acc = fmaf(b2f(v.x), wp[c4 + 0], acc);
                    acc = fmaf(b2f(v.y), wp[c4 + 1], acc);
                    acc = fmaf(b2f(v.z), wp[c4 + 2], acc);
                    acc = fmaf(b2f(v.w), wp[c4 + 3], acc);
                }
            }
        }
    }
    out[((size_t)(b * Tt + t) * 1600 + pix)] = 1.0f / (1.0f + expf(-acc));
}

// ---------------------------------------------------------------------------
extern "C" void kernel_launch(void* const* d_in, const int* in_sizes, int n_in,
                              void* d_out, int out_size, void* d_ws, size_t ws_size,
                              hipStream_t stream)
{
    const float* inp = (const float*)d_in[0];

    char* p = (char*)d_ws;
    const size_t x3sz   = (size_t)Bc * Tt * 1600 * Fc * sizeof(u16);  // 65,536,000
    const size_t slotsz = (size_t)Bc * 1600 * Fc * sizeof(u16);       //  2,048,000
    const size_t csz    = (size_t)NPIX * Fc * sizeof(float);          //  4,096,000
    const size_t wfsz   = (size_t)2 * 24 * 5 * 64 * 8 * sizeof(u16);  //    245,760

    u16* X3 = (u16*)p;                       p += x3sz;
    u16* xr[3];
    for (int l = 0; l < 3; ++l) { xr[l] = (u16*)p; p += 2 * slotsz; }
    // contiguous zero region: h_even x4 then cbuf x4  (24 MB, one init pass)
    char* zb = p;
    u16* h_even[4];
    for (int l = 0; l < 4; ++l) { h_even[l] = (u16*)p; p += slotsz; }
    float* cbuf[4];
    for (int l = 0; l < 4; ++l) { cbuf[l] = (float*)p; p += csz; }
    const size_t zbsz = (size_t)(p - zb);
    u16* h_odd[4];
    for (int l = 0; l < 4; ++l) { h_odd[l] = (u16*)p; p += slotsz; }
    u16* wf[4];
    for (int l = 0; l < 4; ++l) { wf[l] = (u16*)p; p += wfsz; }
    // total ~112 MB

    // ---- one init launch: weight packing + state zeroing ----
    InitArgs ia;
    for (int l = 0; l < 4; ++l) {
        ia.Wx[l] = (const float*)d_in[1 + 7 * l + 0];
        ia.Wh[l] = (const float*)d_in[1 + 7 * l + 1];
        ia.wf[l] = wf[l];
    }
    ia.zb = (float4*)zb;
    ia.zb_quads = (int)(zbsz / 16);
    init_all<<<1024, 256, 0, stream>>>(ia);

    // ---- 35 diagonals: d = l + t ----
    for (int d = 0; d < Tt + 3; ++d) {
        DiagArgs da;
        int na = 0;
        for (int l = 0; l < 4; ++l) {
            int t = d - l;
            if (t < 0 || t >= Tt) continue;
            Stage& s = da.s[na++];
            s.layer = l; s.t = t;
            s.hin  = (t & 1) ? h_odd[l] : h_even[l];
            s.hout = (t & 1) ? h_even[l] : h_odd[l];
            s.cst  = cbuf[l];
            s.wf   = wf[l];
            s.bias = (const float*)d_in[1 + 7 * l + 2];
            s.ga   = (const float*)d_in[1 + 7 * l + 3];
            s.be   = (const float*)d_in[1 + 7 * l + 4];
            s.mu   = (const float*)d_in[1 + 7 * l + 5];
            s.va   = (const float*)d_in[1 + 7 * l + 6];
            s.xin  = (l == 0) ? (const void*)inp
                              : (const void*)(xr[l - 1] + (size_t)(t & 1) * (slotsz / 2));
            s.xout = (l == 3) ? X3 : xr[l] + (size_t)(t & 1) * (slotsz / 2);
        }
        diag_step<<<na * 160, 256, 0, stream>>>(da);
    }

    conv3d_sig_bf16<<<2560, 320, 0, stream>>>(
        X3, (const float*)d_in[29], (const float*)d_in[30], (float*)d_out);
}

// Round 10
// 1917.236 us; speedup vs baseline: 1.3681x; 1.2376x over previous
//
#include <hip/hip_runtime.h>
#include <hip/hip_bf16.h>
#include <cstddef>

typedef __attribute__((ext_vector_type(8))) short short8;
typedef __attribute__((ext_vector_type(4))) float f32x4;
typedef unsigned short u16;
typedef unsigned int u32;

#define Bc 16
#define Tt 32
#define Hh 40
#define Ww 40
#define Fc 40
#define NPIX (Bc*Hh*Ww)   // 25600
#define BN_EPS_ 1e-3f

__device__ __forceinline__ float hsig(float x) {
    return fminf(fmaxf(0.2f * x + 0.5f, 0.0f), 1.0f);
}
__device__ __forceinline__ u16 f2b(float f) {
    __hip_bfloat16 h = __float2bfloat16(f);
    return __builtin_bit_cast(u16, h);
}
__device__ __forceinline__ float b2f(u16 u) {
    return __builtin_bit_cast(float, (u32)u << 16);
}

// ---------------------------------------------------------------------------
// Pack [Wx ; Wh] -> bf16 weights in per-wave MFMA B-fragment order (r5 exact):
//   idx = ((((ng*NKO2 + step)*5 + nt)*64 + lane)*8 + j)
//   n = ng*80 + nt*16 + (lane&15);  k = step*32 + (lane>>4)*8 + j
// Zero for k >= K and padded Wx channels.
// ---------------------------------------------------------------------------
template <int XPAD, int CIN, int NKO2>
__global__ __launch_bounds__(256) void build_wf(const float* __restrict__ Wx,
                                                const float* __restrict__ Wh,
                                                u16* __restrict__ Wf)
{
    constexpr int KPOS = XPAD + Fc;
    constexpr int K    = 9 * KPOS;
    int idx = blockIdx.x * 256 + threadIdx.x;
    if (idx >= 2 * NKO2 * 5 * 64 * 8) return;
    int j    = idx & 7;
    int lane = (idx >> 3) & 63;
    int rest = idx >> 9;
    int nt   = rest % 5;  rest /= 5;
    int step = rest % NKO2; rest /= NKO2;
    int ng   = rest;
    int n = ng * 80 + nt * 16 + (lane & 15);
    int k = step * 32 + (lane >> 4) * 8 + j;
    float v = 0.0f;
    if (k < K) {
        int pos = k / KPOS, cc = k - pos * KPOS;
        if (cc < XPAD) {
            v = (cc < CIN) ? Wx[(pos * CIN + cc) * 160 + n] : 0.0f;
        } else {
            v = Wh[(pos * Fc + (cc - XPAD)) * 160 + n];
        }
    }
    Wf[idx] = f2b(v);
}

// ---------------------------------------------------------------------------
// R5-exact K-loop: barrier-free, B streamed from L2 (coalesced dwordx4,
// fragment order), A from LDS halo, pos<9 guard (zero-init tail fragments),
// full NKO2 trip count (even -> clean unroll-2).
// ---------------------------------------------------------------------------
template <int KPOS, int XPAD, int NKO2>
__device__ __forceinline__ void kloop(const u16* __restrict__ Xs,
                                      const u16* __restrict__ Hs,
                                      const u16* __restrict__ wf,
                                      const int* py, const int* px,
                                      int lquad, f32x4 acc[5][5])
{
#pragma unroll 2
    for (int step = 0; step < NKO2; ++step) {
        short8 bfr[5];
#pragma unroll
        for (int nt = 0; nt < 5; ++nt)
            bfr[nt] = *reinterpret_cast<const short8*>(wf + (size_t)(step * 5 + nt) * 512);

        const int k   = step * 32 + lquad * 8;
        const int pos = k / KPOS;
        const int cc  = k - pos * KPOS;
        short8 afr[5] = {};
        if (pos < 9) {
            const int dy = pos / 3, dx = pos - dy * 3;
            const u16* base; int ch, str;
            if (cc < XPAD) { base = Xs; ch = cc;        str = XPAD; }
            else           { base = Hs; ch = cc - XPAD; str = Fc;   }
#pragma unroll
            for (int mt = 0; mt < 5; ++mt)
                afr[mt] = *reinterpret_cast<const short8*>(
                    &base[((py[mt] + dy) * 42 + px[mt] + dx) * str + ch]);
        }
#pragma unroll
        for (int mt = 0; mt < 5; ++mt)
#pragma unroll
            for (int nt = 0; nt < 5; ++nt)
                acc[mt][nt] = __builtin_amdgcn_mfma_f32_16x16x32_bf16(
                    afr[mt], bfr[nt], acc[mt][nt], 0, 0, 0);
    }
}

// ---------------------------------------------------------------------------
// Diagonal step, FINE-GRAIN tiling: M-tile 80 pixels (2 rows), 128-thread
// blocks (2 waves: ng 0/1, each 80M x 80N, acc 5x5). Halo = 4 rows ->
// LDS 26.9 KB -> 4 blocks/CU (vs 2 at M=160): halves the occupancy-round
// quantization loss per diagonal. Per-wave K-loop identical to r5.
// ---------------------------------------------------------------------------
struct Stage {
    const void* xin;   // l==0: fp32 input base; l>=1: bf16 X-ring slot
    const u16* hin;    // bf16 [NPIX][40]
    u16*       hout;
    float*     cst;    // fp32 [NPIX][40]
    const u16* wf;     // fragment-ordered weights
    const float* bias; const float* ga; const float* be;
    const float* mu;   const float* va;
    u16*       xout;
    int layer; int t;
};
struct DiagArgs { Stage s[4]; };

__global__ __launch_bounds__(128, 2) void diag_step(DiagArgs args)
{
    // halo (layers>=1): 4 rows x 42 px x (40+40) ch = 13440 u16 = 26880 B
    // zs overlay: 40 x 164 fp32 = 26240 B (fits)
    __shared__ __align__(16) u16 smem[13440];

    const int sidx = blockIdx.x / 320;
    const int blk  = blockIdx.x - sidx * 320;
    const Stage& st = args.s[sidx];
    const int l    = st.layer;
    const int XPAD = (l == 0) ? 8 : 40;

    u16* Xs = smem;
    u16* Hs = smem + 4 * 42 * XPAD;
    float* zs = reinterpret_cast<float*>(smem);   // epilogue overlay

    const int tid   = threadIdx.x;          // 0..127
    const int P0    = blk * 80;             // 1600 % 80 == 0: never straddles batch
    const int bimg  = P0 / 1600;
    const int P0l   = P0 - bimg * 1600;
    const int P0row = P0l / 40;             // 0,2,...,38

    // ---- stage Hs halo: 4 rows x 40 px x 40 ch ----
    const u16* hp = st.hin + (size_t)bimg * 1600 * Fc;
    for (int i = tid; i < 4 * 40 * 10; i += 128) {
        int s = i / 400, rem = i - s * 400;
        int px_ = rem / 10, c4 = rem - px_ * 10;
        int gy = P0row - 1 + s;
        uint2 v = make_uint2(0u, 0u);
        if (gy >= 0 && gy < Hh)
            v = *reinterpret_cast<const uint2*>(hp + ((size_t)gy * Ww + px_) * Fc + c4 * 4);
        *reinterpret_cast<uint2*>(&Hs[(s * 42 + px_ + 1) * Fc + c4 * 4]) = v;
    }
    for (int i = tid; i < 4 * 2 * 10; i += 128) {   // x-halo columns
        int s = i / 20, rem = i - s * 20;
        int side = rem / 10, c4 = rem - side * 10;
        *reinterpret_cast<uint2*>(&Hs[(s * 42 + (side ? 41 : 0)) * Fc + c4 * 4]) =
            make_uint2(0u, 0u);
    }

    // ---- stage Xs halo ----
    if (l == 0) {
        const float* xf = (const float*)st.xin + (size_t)(bimg * Tt + st.t) * 1600;
        for (int i = tid; i < 4 * 42; i += 128) {
            int s = i / 42, xc = i - s * 42;
            int gy = P0row - 1 + s, gx = xc - 1;
            u16 tmp[8] = {0, 0, 0, 0, 0, 0, 0, 0};
            if (gy >= 0 && gy < Hh && gx >= 0 && gx < Ww)
                tmp[0] = f2b(xf[(size_t)gy * Ww + gx]);
            *reinterpret_cast<uint4*>(&Xs[(s * 42 + xc) * 8]) =
                *reinterpret_cast<const uint4*>(tmp);
        }
    } else {
        const u16* xb = (const u16*)st.xin + (size_t)bimg * 1600 * Fc;
        for (int i = tid; i < 4 * 40 * 10; i += 128) {
            int s = i / 400, rem = i - s * 400;
            int px_ = rem / 10, c4 = rem - px_ * 10;
            int gy = P0row - 1 + s;
            uint2 v = make_uint2(0u, 0u);
            if (gy >= 0 && gy < Hh)
                v = *reinterpret_cast<const uint2*>(xb + ((size_t)gy * Ww + px_) * Fc + c4 * 4);
            *reinterpret_cast<uint2*>(&Xs[(s * 42 + px_ + 1) * Fc + c4 * 4]) = v;
        }
        for (int i = tid; i < 4 * 2 * 10; i += 128) {
            int s = i / 20, rem = i - s * 20;
            int side = rem / 10, c4 = rem - side * 10;
            *reinterpret_cast<uint2*>(&Xs[(s * 42 + (side ? 41 : 0)) * Fc + c4 * 4]) =
                make_uint2(0u, 0u);
        }
    }

    // ---- wave constants: 2 waves, ng = wave id, each 80M x 80N ----
    const int lane  = tid & 63;
    const int ng    = tid >> 6;       // 0..1
    const int lcol  = lane & 15;
    const int lquad = lane >> 4;

    int py[5], px[5];
#pragma unroll
    for (int mt = 0; mt < 5; ++mt) {
        int mrow = mt * 16 + lcol;    // 0..79
        py[mt] = mrow / 40;           // 0..1
        px[mt] = mrow - py[mt] * 40;
    }

    f32x4 acc[5][5] = {};

    __syncthreads();   // halos staged; K-loop is barrier-free

    if (l == 0) {
        const u16* wf = st.wf + (size_t)ng * 14 * 5 * 512 + (size_t)lane * 8;
        kloop<48, 8, 14>(Xs, Hs, wf, py, px, lquad, acc);
    } else {
        const u16* wf = st.wf + (size_t)ng * 24 * 5 * 512 + (size_t)lane * 8;
        kloop<80, 40, 24>(Xs, Hs, wf, py, px, lquad, acc);
    }

    __syncthreads();   // all waves done reading halo LDS before zs overlay

    // ---- epilogue: 2 chunks of 40 rows; mt=2 tile (rows 32..47) straddles ----
    u16* hob = st.hout;
    float* cb = st.cst;
    u16* xob = (l == 3)
        ? st.xout + ((size_t)(bimg * Tt + st.t) * 1600 + P0l) * Fc
        : st.xout + ((size_t)bimg * 1600 + P0l) * Fc;

    for (int q = 0; q < 2; ++q) {
#pragma unroll
        for (int mt = 0; mt < 5; ++mt)
#pragma unroll
            for (int nt = 0; nt < 5; ++nt) {
                int ncol = ng * 80 + nt * 16 + lcol;
#pragma unroll
                for (int r = 0; r < 4; ++r) {
                    int row = mt * 16 + lquad * 4 + r;   // 0..79
                    if ((row >= q * 40) && (row < q * 40 + 40))
                        zs[(row - q * 40) * 164 + ncol] = acc[mt][nt][r];
                }
            }
        __syncthreads();
        for (int i = tid; i < 1600; i += 128) {
            int m = i / 40, f = i - m * 40;
            float zi = zs[m * 164 + f]        + st.bias[f];
            float zf = zs[m * 164 + 40 + f]   + st.bias[40 + f];
            float zg = zs[m * 164 + 80 + f]   + st.bias[80 + f];
            float zo = zs[m * 164 + 120 + f]  + st.bias[120 + f];
            int pl = q * 40 + m;                       // pixel within block tile
            size_t gp = (size_t)(P0 + pl) * Fc + f;
            float cold = cb[gp];
            float cn = hsig(zf) * cold + hsig(zi) * tanhf(zg);
            float hn = hsig(zo) * tanhf(cn);
            cb[gp] = cn;
            hob[gp] = f2b(hn);
            float sc = st.ga[f] * rsqrtf(st.va[f] + BN_EPS_);
            xob[(size_t)pl * Fc + f] = f2b((hn - st.mu[f]) * sc + st.be[f]);
        }
        __syncthreads();   // zs reads done before next chunk's overwrite
    }
}

// ---------------------------------------------------------------------------
// Conv3D (3x3x3 SAME) + bias + sigmoid — r5-exact (measured 79-81 us).
// ---------------------------------------------------------------------------
__global__ __launch_bounds__(320) void conv3d_sig_bf16(
    const u16* __restrict__ X,        // bf16 [B,T,1600,40]
    const float* __restrict__ W3,     // [3,3,3,40,1]
    const float* __restrict__ b3,
    float* __restrict__ out)          // [B,T,1600]
{
    __shared__ float ws[27 * Fc];
    for (int i = threadIdx.x; i < 27 * Fc; i += 320) ws[i] = W3[i];
    __syncthreads();

    const int bid   = blockIdx.x;           // 2560 blocks
    const int xcd   = bid & 7;
    const int local = bid >> 3;             // 0..319
    const int b     = xcd * 2 + (local / 160);
    const int rem   = local - (local / 160) * 160;
    const int t     = rem / 5;
    const int s     = rem - t * 5;
    const int pix   = s * 320 + threadIdx.x;
    const int y     = pix / 40;
    const int x     = pix - y * 40;

    float acc = b3[0];
    for (int dt = 0; dt < 3; ++dt) {
        int tc = t + dt - 1;
        if (tc < 0 || tc >= Tt) continue;
        for (int dy = 0; dy < 3; ++dy) {
            int yy = y + dy - 1;
            if (yy < 0 || yy >= Hh) continue;
            for (int dx = 0; dx < 3; ++dx) {
                int xx = x + dx - 1;
                if (xx < 0 || xx >= Ww) continue;
                const u16* xp = X + ((size_t)(b * Tt + tc) * 1600 + yy * 40 + xx) * Fc;
                const float* wp = ws + ((dt * 3 + dy) * 3 + dx) * Fc;
#pragma unroll
                for (int c4 = 0; c4 < Fc; c4 += 4) {
                    ushort4 v = *reinterpret_cast<const ushort4*>(xp + c4);
                    acc = fmaf(b2f(v.x), wp[c4 + 0], acc);
                    acc = fmaf(b2f(v.y), wp[c4 + 1], acc);
                    acc = fmaf(b2f(v.z), wp[c4 + 2], acc);
                    acc = fmaf(b2f(v.w), wp[c4 + 3], acc);
                }
            }
        }
    }
    out[((size_t)(b * Tt + t) * 1600 + pix)] = 1.0f / (1.0f + expf(-acc));
}

// ---------------------------------------------------------------------------
extern "C" void kernel_launch(void* const* d_in, const int* in_sizes, int n_in,
                              void* d_out, int out_size, void* d_ws, size_t ws_size,
                              hipStream_t stream)
{
    const float* inp = (const float*)d_in[0];

    char* p = (char*)d_ws;
    const size_t x3sz   = (size_t)Bc * Tt * 1600 * Fc * sizeof(u16);  // 65,536,000
    const size_t slotsz = (size_t)Bc * 1600 * Fc * sizeof(u16);       //  2,048,000
    const size_t csz    = (size_t)NPIX * Fc * sizeof(float);          //  4,096,000
    const size_t wfsz   = (size_t)2 * 24 * 5 * 64 * 8 * sizeof(u16);  //    245,760

    u16* X3 = (u16*)p;                       p += x3sz;
    u16* xr[3];
    for (int l = 0; l < 3; ++l) { xr[l] = (u16*)p; p += 2 * slotsz; }
    u16* hb[8];
    for (int i = 0; i < 8; ++i) { hb[i] = (u16*)p; p += slotsz; }
    float* cbuf[4];
    for (int l = 0; l < 4; ++l) { cbuf[l] = (float*)p; p += csz; }
    u16* wf[4];
    for (int l = 0; l < 4; ++l) { wf[l] = (u16*)p; p += wfsz; }
    // total ~112 MB

    for (int l = 0; l < 4; ++l) {
        const float* Wx = (const float*)d_in[1 + 7 * l + 0];
        const float* Wh = (const float*)d_in[1 + 7 * l + 1];
        if (l == 0)
            build_wf<8, 1, 14><<<(2 * 14 * 5 * 512 + 255) / 256, 256, 0, stream>>>(Wx, Wh, wf[l]);
        else
            build_wf<40, 40, 24><<<(2 * 24 * 5 * 512 + 255) / 256, 256, 0, stream>>>(Wx, Wh, wf[l]);
        hipMemsetAsync(hb[l * 2], 0, slotsz, stream);
        hipMemsetAsync(cbuf[l], 0, csz, stream);
    }

    // ---- 35 diagonals: d = l + t ----
    for (int d = 0; d < Tt + 3; ++d) {
        DiagArgs da;
        int na = 0;
        for (int l = 0; l < 4; ++l) {
            int t = d - l;
            if (t < 0 || t >= Tt) continue;
            Stage& s = da.s[na++];
            s.layer = l; s.t = t;
            s.hin  = hb[l * 2 + (t & 1)];
            s.hout = hb[l * 2 + ((t + 1) & 1)];
            s.cst  = cbuf[l];
            s.wf   = wf[l];
            s.bias = (const float*)d_in[1 + 7 * l + 2];
            s.ga   = (const float*)d_in[1 + 7 * l + 3];
            s.be   = (const float*)d_in[1 + 7 * l + 4];
            s.mu   = (const float*)d_in[1 + 7 * l + 5];
            s.va   = (const float*)d_in[1 + 7 * l + 6];
            s.xin  = (l == 0) ? (const void*)inp
                              : (const void*)(xr[l - 1] + (size_t)(t & 1) * (slotsz / 2));
            s.xout = (l == 3) ? X3 : xr[l] + (size_t)(t & 1) * (slotsz / 2);
        }
        diag_step<<<na * 320, 128, 0, stream>>>(da);
    }

    conv3d_sig_bf16<<<2560, 320, 0, stream>>>(
        X3, (const float*)d_in[29], (const float*)d_in[30], (float*)d_out);
}